// Round 7
// baseline (440.114 us; speedup 1.0000x reference)
//
#include <hip/hip_runtime.h>
#include <math.h>

#define EPSV 1e-10f

typedef _Float16 f16x8 __attribute__((ext_vector_type(8)));
typedef _Float16 f16x4 __attribute__((ext_vector_type(4)));
typedef float f32x4 __attribute__((ext_vector_type(4)));

// ---------------- LDS layout (bytes) ----------------
#define OFF_W1T  0       // 16384: W1t[n][k] f16 swz      (P0: AU f32 64x64)
#define OFF_W2T  16384   // 8192:  W2t[n2][h] f16 swz
#define OFF_M2T  24576   // 8192:  M2t[n3][h] f16 swz (M2 = W2 . AW1x)
#define OFF_X    32768   // 16384: 4 wave-slots x 4096B
                         //   main: 16 rows x 256B  (P0: uS f32; P2a: cst partials)
                         //   tail: 16 rows x 240B + sE(64B) + sM(64B)
#define OFF_V    49152   // 5120:  sV[g][n], g < 20
#define OFF_MASK 54272   // 256:   4 waves x 16 rows
#define SMEM_SZ  54528   // 3 blocks/CU (3*54528 = 163584 <= 163840)

__device__ __forceinline__ f16x8 cvt_f16x8(const float4 a, const float4 b) {
  f16x8 h;
  h[0] = (_Float16)a.x; h[1] = (_Float16)a.y; h[2] = (_Float16)a.z; h[3] = (_Float16)a.w;
  h[4] = (_Float16)b.x; h[5] = (_Float16)b.y; h[6] = (_Float16)b.z; h[7] = (_Float16)b.w;
  return h;
}

// ---------------------------------------------------------------------------
// Fully fused kernel. S-blocks [0,1024): 20 q-groups each (block s covers the
// q-groups of batch element b = s>>1). I-blocks [1024,1152): 4 groups (1/wave).
// A wave owns whole groups (S: 5, I: 1); zero __syncthreads in the main loop.
// After a wave's last group it release-fences and bumps cnt[b]; the 9th
// contributor (8 S-waves + 1 I-wave) runs the beta-attention + final-MLP tail
// for b on that wave. Output is winner-independent.
// ---------------------------------------------------------------------------
__global__ __launch_bounds__(256, 3) void agg_kernel(
    const int nSblk,
    const int* __restrict__ idsS, const int* __restrict__ uidS,
    const int* __restrict__ idsI, const int* __restrict__ uidI,
    const float* __restrict__ user_table, const float* __restrict__ item_table,
    const float* __restrict__ rate_table,
    const float* __restrict__ gv_W1, const float* __restrict__ gv_b1,
    const float* __restrict__ gv_W2, const float* __restrict__ gv_b2,
    const float* __restrict__ atti_W1, const float* __restrict__ atti_b1,
    const float* __restrict__ atti_W2, const float* __restrict__ atti_b2,
    const float* __restrict__ agg_W, const float* __restrict__ agg_b,
    const float* __restrict__ attu_W1, const float* __restrict__ attu_b1,
    const float* __restrict__ attu_W2, const float* __restrict__ attu_b2,
    const float* __restrict__ aggn_W, const float* __restrict__ aggn_b,
    const float* __restrict__ cm_W1, const float* __restrict__ cm_b1,
    const float* __restrict__ cm_W2, const float* __restrict__ cm_b2,
    const float* __restrict__ cm_W3, const float* __restrict__ cm_b3,
    const int* __restrict__ u_user_pad,
    float* __restrict__ hoI, float* __restrict__ hiI, int* __restrict__ cnt,
    float* __restrict__ final_out) {
  __shared__ __align__(16) char smem[SMEM_SZ];
  const int tid = threadIdx.x;
  const int wave = tid >> 6, lane = tid & 63;
  const int quad = lane >> 4, mrow = lane & 15;

  const bool isS = (int)blockIdx.x < nSblk;
  const int NG = isS ? 20 : 4;
  const int P = isS ? 40 : 100;
  const int nGrp = isS ? 5 : 1;  // groups per wave
  const int tpg = isS ? 3 : 8;   // 16-row tiles per group
  const int* __restrict__ ids = isS ? idsS : idsI;
  const int* __restrict__ uidp = isS ? uidS : uidI;
  float* __restrict__ out = isS ? hoI : hiI;
  const int gbase = isS ? (int)blockIdx.x * 20 : ((int)blockIdx.x - nSblk) * 4;

  float* sV = (float*)(smem + OFF_V);
  float* sMaskF = (float*)(smem + OFF_MASK);
  char* smX = smem + OFF_X;
  char* smXw = smX + wave * 4096;  // wave-private slot
  float* csW = (float*)smXw;       // epilogue c vector (tile dead then)

  // ---- P0: uS (X region) + AU = AW1u^T f32 (W1T region, f4-swizzled) ----
  {
    float* uS = (float*)smX;
    float* AU = (float*)(smem + OFF_W1T);
    for (int t = tid; t < NG * 64; t += 256) {
      const int g = t >> 6, f = t & 63;
      uS[t] = user_table[(size_t)uidp[gbase + g] * 64 + f];
    }
    for (int o = tid; o < 1024; o += 256) {  // AU[j][k] = atti_W1[64+k][j]
      const int k = o >> 4, fb = o & 15;
      const float4 v = ((const float4*)(atti_W1 + (64 + k) * 64))[fb];
      const float* vp = (const float*)&v;
#pragma unroll
      for (int c = 0; c < 4; ++c) {
        const int j = fb * 4 + c;
        AU[j * 64 + (((k >> 2) ^ (j & 15)) << 2) + (k & 3)] = vp[c];
      }
    }
  }
  __syncthreads();
  // ---- P1: v[g][j] = u[g] . AW1u[:,j] ----
  {
    const float4* u4 = (const float4*)smX;
    const float4* a4 = (const float4*)(smem + OFF_W1T);
    for (int t = tid; t < NG * 64; t += 256) {
      const int g = t >> 6, j = t & 63;
      float s = 0.f;
#pragma unroll 4
      for (int kb = 0; kb < 16; ++kb) {
        const float4 uu = u4[g * 16 + kb];
        const float4 aa = a4[j * 16 + (kb ^ (j & 15))];
        s += uu.x * aa.x + uu.y * aa.y + uu.z * aa.z + uu.w * aa.w;
      }
      sV[t] = s;
    }
  }
  __syncthreads();
  // ---- P2a: W1T/W2T f16 staging (coalesced) + cst partials -> X ----
  {
    for (int o = tid; o < 2048; o += 256) {  // W1T[n][k], k in 0..127
      const int k = o >> 4, fb = o & 15;
      const float4 v = ((const float4*)(gv_W1 + k * 64))[fb];
      const float* vp = (const float*)&v;
#pragma unroll
      for (int c = 0; c < 4; ++c) {
        const int n = fb * 4 + c;
        *(_Float16*)(smem + OFF_W1T + n * 256 + ((((k >> 3) ^ (n & 7))) << 4) +
                     ((k & 7) << 1)) = (_Float16)vp[c];
      }
    }
    for (int o = tid; o < 1024; o += 256) {  // W2T[n2][h]
      const int h = o >> 4, fb = o & 15;
      const float4 v = ((const float4*)(gv_W2 + h * 64))[fb];
      const float* vp = (const float*)&v;
#pragma unroll
      for (int c = 0; c < 4; ++c) {
        const int n = fb * 4 + c;
        *(_Float16*)(smem + OFF_W2T + n * 128 + ((((h >> 3) ^ (n & 7))) << 4) +
                     ((h & 7) << 1)) = (_Float16)vp[c];
      }
    }
    float* sCstP = (float*)smX;  // uS dead after P1
    const int n = tid & 63, jh = tid >> 6;
    float p = 0.f;
#pragma unroll 4
    for (int jj = 0; jj < 16; ++jj) {
      const int j = jh * 16 + jj;
      p = fmaf(gv_b2[j], atti_W1[j * 64 + n], p);
    }
    sCstP[jh * 64 + n] = p;
  }
  // per-lane constant preloads (global, L2-hot)
  float b1r[16], b2v[4], aw2v[4];
#pragma unroll
  for (int nt = 0; nt < 4; ++nt) {
#pragma unroll
    for (int rg = 0; rg < 4; ++rg) b1r[nt * 4 + rg] = gv_b1[nt * 16 + quad * 4 + rg];
    b2v[nt] = gv_b2[nt * 16 + mrow];
    aw2v[nt] = atti_W2[nt * 16 + mrow];
  }
  const float ab2 = atti_b2[0];

  // ---- gather prefetch (wave-private tile) ----
  float4 pa[4], pb[4];
  float msk[4];
  auto do_prefetch = [&](int gi2, int tt2) {
    const int g2 = gbase + wave + 4 * gi2;
#pragma unroll
    for (int k = 0; k < 4; ++k) {
      const int it = tt2 * 16 + quad + 4 * k;
      int iid = 0, rid = 0;
      float m = 0.f;
      if (it < P) {
        const int2 pr = ((const int2*)ids)[(size_t)g2 * P + it];
        iid = pr.x; rid = pr.y;
        m = pr.x > 0 ? 1.f : 0.f;
      }
      msk[k] = m;
      const float* src = (mrow < 8) ? item_table + (size_t)iid * 64 + mrow * 8
                                    : rate_table + (size_t)rid * 64 + (mrow - 8) * 8;
      pa[k] = ((const float4*)src)[0];
      pb[k] = ((const float4*)src)[1];
    }
  };
  do_prefetch(0, 0);  // in flight across P2b
  __syncthreads();    // B3: W1T/W2T/cstP ready
  // ---- P2b: M2T via MFMA (A,B from L2-hot global) + cstv to registers ----
  float cstv[4];
  {
    f16x8 aM[2];
#pragma unroll
    for (int ks = 0; ks < 2; ++ks) {
      f16x8 t;
#pragma unroll
      for (int j = 0; j < 8; ++j)
        t[j] = (_Float16)atti_W1[(ks * 32 + quad * 8 + j) * 64 + (wave * 16 + mrow)];
      aM[ks] = t;
    }
#pragma unroll
    for (int ht = 0; ht < 4; ++ht) {
      f32x4 c = {0.f, 0.f, 0.f, 0.f};
#pragma unroll
      for (int ks = 0; ks < 2; ++ks) {
        const float* s = gv_W2 + (ht * 16 + mrow) * 64 + ks * 32 + quad * 8;
        f16x8 b;
#pragma unroll
        for (int j = 0; j < 8; ++j) b[j] = (_Float16)s[j];
        c = __builtin_amdgcn_mfma_f32_16x16x32_f16(aM[ks], b, c, 0, 0, 0);
      }
      const int h = ht * 16 + mrow;
#pragma unroll
      for (int rg = 0; rg < 4; ++rg) {
        const int n3 = wave * 16 + quad * 4 + rg;
        *(_Float16*)(smem + OFF_M2T + n3 * 128 + ((((h >> 3) ^ (n3 & 7))) << 4) +
                     ((h & 7) << 1)) = (_Float16)c[rg];
      }
    }
    const float* sCstP = (const float*)smX;
#pragma unroll
    for (int nt = 0; nt < 4; ++nt) {
      const int n = nt * 16 + mrow;
      cstv[nt] = atti_b1[n] + sCstP[n] + sCstP[64 + n] + sCstP[128 + n] +
                 sCstP[192 + n];
    }
  }
  __syncthreads();  // B4: M2T ready; X region free for staging

  // =================== barrier-free main loop ===================
  for (int gi = 0; gi < nGrp; ++gi) {
    const int g = wave + 4 * gi;
    float vv[4];
#pragma unroll
    for (int nt = 0; nt < 4; ++nt) vv[nt] = sV[g * 64 + nt * 16 + mrow];
    float pnum[4] = {0.f, 0.f, 0.f, 0.f};
    float pden = 0.f;
    for (int tt = 0; tt < tpg; ++tt) {
      // stage In tile from prefetched regs (wave-private rows)
#pragma unroll
      for (int k = 0; k < 4; ++k) {
        const int r = quad + 4 * k;
        *(f16x8*)(smXw + r * 256 + ((mrow ^ (r & 7)) << 4)) = cvt_f16x8(pa[k], pb[k]);
        if (mrow == 0) sMaskF[wave * 16 + r] = msk[k];
      }
      // issue next prefetch
      {
        int ngi = gi, ntt = tt + 1;
        if (ntt == tpg) { ntt = 0; ngi = gi + 1; }
        if (ngi < nGrp) do_prefetch(ngi, ntt);
      }
      // B-frags of In (read all 4 ks before Ht overwrites the low half)
      f16x8 bIn[4];
#pragma unroll
      for (int ks = 0; ks < 4; ++ks)
        bIn[ks] = *(const f16x8*)(smXw + mrow * 256 +
                                  (((ks * 4 + quad) ^ (mrow & 7)) << 4));
      // ---- layer1 (transposed): H^T -> in-place b64 writes ----
#pragma unroll
      for (int nt = 0; nt < 4; ++nt) {
        f32x4 c = {0.f, 0.f, 0.f, 0.f};
#pragma unroll
        for (int ks = 0; ks < 4; ++ks) {
          const f16x8 aW = *(const f16x8*)(smem + OFF_W1T + (nt * 16 + mrow) * 256 +
                                           (((ks * 4 + quad) ^ (mrow & 7)) << 4));
          c = __builtin_amdgcn_mfma_f32_16x16x32_f16(aW, bIn[ks], c, 0, 0, 0);
        }
        f16x4 hv;
#pragma unroll
        for (int rg = 0; rg < 4; ++rg)
          hv[rg] = (_Float16)fmaxf(c[rg] + b1r[nt * 4 + rg], 0.f);
        *(f16x4*)(smXw + mrow * 256 +
                  (((nt * 2 + (quad >> 1)) ^ (mrow & 7)) << 4) +
                  ((quad & 1) << 3)) = hv;
      }
      // ---- shared A-frags (H rows) for layer2 + attention ----
      f16x8 a2[2];
#pragma unroll
      for (int ks = 0; ks < 2; ++ks)
        a2[ks] = *(const f16x8*)(smXw + mrow * 256 +
                                 (((ks * 4 + quad) ^ (mrow & 7)) << 4));
      float mk[4];
#pragma unroll
      for (int rg = 0; rg < 4; ++rg) mk[rg] = sMaskF[wave * 16 + quad * 4 + rg];
      f32x4 x2a[4];
      float tl[4] = {0.f, 0.f, 0.f, 0.f};
#pragma unroll
      for (int nt = 0; nt < 4; ++nt) {
        f32x4 c = {0.f, 0.f, 0.f, 0.f}, d = {0.f, 0.f, 0.f, 0.f};
#pragma unroll
        for (int ks = 0; ks < 2; ++ks) {
          const f16x8 bW = *(const f16x8*)(smem + OFF_W2T + (nt * 16 + mrow) * 128 +
                                           (((ks * 4 + quad) ^ (mrow & 7)) << 4));
          c = __builtin_amdgcn_mfma_f32_16x16x32_f16(a2[ks], bW, c, 0, 0, 0);
        }
#pragma unroll
        for (int ks = 0; ks < 2; ++ks) {
          const f16x8 bM = *(const f16x8*)(smem + OFF_M2T + (nt * 16 + mrow) * 128 +
                                           (((ks * 4 + quad) ^ (mrow & 7)) << 4));
          d = __builtin_amdgcn_mfma_f32_16x16x32_f16(a2[ks], bM, d, 0, 0, 0);
        }
#pragma unroll
        for (int rg = 0; rg < 4; ++rg) x2a[nt][rg] = c[rg] + b2v[nt];
#pragma unroll
        for (int rg = 0; rg < 4; ++rg) {
          const float hh = fmaxf(d[rg] + cstv[nt] + mk[rg] * vv[nt], 0.f);
          tl[rg] = fmaf(hh, aw2v[nt], tl[rg]);
        }
      }
      float e[4];
#pragma unroll
      for (int rg = 0; rg < 4; ++rg) {
        float t = tl[rg];
        t += __shfl_xor(t, 1); t += __shfl_xor(t, 2);
        t += __shfl_xor(t, 4); t += __shfl_xor(t, 8);
        e[rg] = __expf(t + ab2) * mk[rg];
        pden += e[rg];
      }
#pragma unroll
      for (int nt = 0; nt < 4; ++nt) {
        pnum[nt] = fmaf(e[0], x2a[nt][0], pnum[nt]);
        pnum[nt] = fmaf(e[1], x2a[nt][1], pnum[nt]);
        pnum[nt] = fmaf(e[2], x2a[nt][2], pnum[nt]);
        pnum[nt] = fmaf(e[3], x2a[nt][3], pnum[nt]);
      }
    }
    // ---- group flush (wave-local): quad-reduce + agg matvec + store ----
    float dsum = pden;
    dsum += __shfl_xor(dsum, 16); dsum += __shfl_xor(dsum, 32);
    const float rd = 1.f / (dsum + EPSV);
#pragma unroll
    for (int nt = 0; nt < 4; ++nt) {
      float s = pnum[nt];
      s += __shfl_xor(s, 16); s += __shfl_xor(s, 32);
      if (quad == 0) csW[nt * 16 + mrow] = s * rd;
    }
    float acc = agg_b[lane];
#pragma unroll 8
    for (int k = 0; k < 64; ++k) acc = fmaf(csW[k], agg_W[k * 64 + lane], acc);
    out[(size_t)(gbase + g) * 64 + lane] = fmaxf(acc, 0.f);
  }

  // =================== last-finisher fused stage2 tail ===================
  const int b = isS ? ((int)blockIdx.x >> 1) : (gbase + wave);
  __threadfence();  // release hoI/hiI stores
  int old = 0;
  if (lane == 0) old = atomicAdd(cnt + b, 1);
  old = __shfl(old, 0);
  if (old == 8) {
    __threadfence();  // acquire all producers' stores
    char* tX = smXw;  // 16 rows x 240B
    float* tE = (float*)(smXw + 3840);
    float* tM = (float*)(smXw + 3904);
    // attu_W1^T B-frags from global (f32 -> f16), once
    f16x8 bw[4][4];
#pragma unroll
    for (int nt = 0; nt < 4; ++nt)
#pragma unroll
      for (int ks = 0; ks < 4; ++ks) {
        f16x8 t;
#pragma unroll
        for (int j = 0; j < 8; ++j)
          t[j] = (_Float16)attu_W1[(ks * 32 + quad * 8 + j) * 64 + nt * 16 + mrow];
        bw[nt][ks] = t;
      }
    float tb1[4], tw2[4];
#pragma unroll
    for (int nt = 0; nt < 4; ++nt) {
      tb1[nt] = attu_b1[nt * 16 + mrow];
      tw2[nt] = attu_W2[nt * 16 + mrow];
    }
    const float tb2 = attu_b2[0];

    float numer = 0.f, tden = 0.f;
    for (int tt = 0; tt < 3; ++tt) {
      // stage 16 concat rows (cols 0..63 = hoI, 64..127 = nbr emb)
#pragma unroll
      for (int k = 0; k < 4; ++k) {
        const int u = lane + (k << 6);
        const int r = u >> 4, bb = u & 15;
        const int q = tt * 16 + r;
        const int qc = q < 40 ? q : 39;
        int uid = 0;
        float m = 0.f;
        if (q < 40) {
          uid = u_user_pad[b * 40 + q];
          m = uid > 0 ? 1.f : 0.f;
        }
        const float* src = (bb < 8)
                               ? hoI + ((size_t)b * 40 + qc) * 64 + bb * 8
                               : user_table + (size_t)uid * 64 + (bb - 8) * 8;
        const float4 p = ((const float4*)src)[0];
        const float4 q4 = ((const float4*)src)[1];
        *(f16x8*)(tX + r * 240 + (bb << 4)) = cvt_f16x8(p, q4);
        if (bb == 0) tM[r] = m;
      }
      f16x8 a[4];
#pragma unroll
      for (int ks = 0; ks < 4; ++ks)
        a[ks] = *(const f16x8*)(tX + mrow * 240 + ((ks * 4 + quad) << 4));
      float mk[4];
#pragma unroll
      for (int rg = 0; rg < 4; ++rg) mk[rg] = tM[quad * 4 + rg];
      float tl[4] = {0.f, 0.f, 0.f, 0.f};
#pragma unroll
      for (int nt = 0; nt < 4; ++nt) {
        f32x4 d = {0.f, 0.f, 0.f, 0.f};
#pragma unroll
        for (int ks = 0; ks < 4; ++ks)
          d = __builtin_amdgcn_mfma_f32_16x16x32_f16(a[ks], bw[nt][ks], d, 0, 0, 0);
#pragma unroll
        for (int rg = 0; rg < 4; ++rg) {
          const float h = fmaxf(d[rg] + tb1[nt], 0.f);
          tl[rg] = fmaf(h, tw2[nt], tl[rg]);
        }
      }
      float e[4];
#pragma unroll
      for (int rg = 0; rg < 4; ++rg) {
        float t = tl[rg];
        t += __shfl_xor(t, 1); t += __shfl_xor(t, 2);
        t += __shfl_xor(t, 4); t += __shfl_xor(t, 8);
        e[rg] = __expf(t + tb2) * mk[rg];
        tden += e[rg];
      }
      if (mrow == 0) {
#pragma unroll
        for (int rg = 0; rg < 4; ++rg) tE[quad * 4 + rg] = e[rg];
      }
#pragma unroll 4
      for (int r = 0; r < 16; ++r) {
        const float er = tE[r];
        const float xv = (float)*(const _Float16*)(tX + r * 240 + ((lane >> 3) << 4) +
                                                   ((lane & 7) << 1));
        numer = fmaf(er, xv, numer);
      }
    }
    tden += __shfl_xor(tden, 16);
    tden += __shfl_xor(tden, 32);
    const float hagg = numer / (tden + EPSV);

    float* sB = (float*)smXw;  // rows dead now
    sB[128 + lane] = hagg;
    sB[lane] = hiI[(size_t)b * 64 + lane];
    float acc = aggn_b[lane];
#pragma unroll 8
    for (int k = 0; k < 64; ++k) acc = fmaf(sB[128 + k], aggn_W[k * 64 + lane], acc);
    sB[64 + lane] = fmaxf(acc, 0.f);
    float c1 = cm_b1[lane];
#pragma unroll 8
    for (int k = 0; k < 128; ++k) c1 = fmaf(sB[k], cm_W1[k * 64 + lane], c1);
    sB[128 + lane] = fmaxf(c1, 0.f);
    float c2 = cm_b2[lane];
#pragma unroll 8
    for (int k = 0; k < 64; ++k) c2 = fmaf(sB[128 + k], cm_W2[k * 64 + lane], c2);
    sB[lane] = fmaxf(c2, 0.f);
    float c3 = cm_b3[lane];
#pragma unroll 8
    for (int k = 0; k < 64; ++k) c3 = fmaf(sB[k], cm_W3[k * 64 + lane], c3);
    final_out[(size_t)b * 64 + lane] = fmaxf(c3, 0.f);
  }
}

extern "C" void kernel_launch(void* const* d_in, const int* in_sizes, int n_in,
                              void* d_out, int out_size, void* d_ws, size_t ws_size,
                              hipStream_t stream) {
  const int* uids = (const int*)d_in[0];
  const int* u_item_pad = (const int*)d_in[1];
  const int* u_user_pad = (const int*)d_in[2];
  const int* u_user_item_pad = (const int*)d_in[3];
  const float* user_table = (const float*)d_in[4];
  const float* item_table = (const float*)d_in[5];
  const float* rate_table = (const float*)d_in[6];
  const float* gv_W1 = (const float*)d_in[7];
  const float* gv_b1 = (const float*)d_in[8];
  const float* gv_W2 = (const float*)d_in[9];
  const float* gv_b2 = (const float*)d_in[10];
  const float* atti_W1 = (const float*)d_in[11];
  const float* atti_b1 = (const float*)d_in[12];
  const float* atti_W2 = (const float*)d_in[13];
  const float* atti_b2 = (const float*)d_in[14];
  const float* agg_W = (const float*)d_in[15];
  const float* agg_b = (const float*)d_in[16];
  const float* attu_W1 = (const float*)d_in[17];
  const float* attu_b1 = (const float*)d_in[18];
  const float* attu_W2 = (const float*)d_in[19];
  const float* attu_b2 = (const float*)d_in[20];
  const float* aggn_W = (const float*)d_in[21];
  const float* aggn_b = (const float*)d_in[22];
  const float* cm_W1 = (const float*)d_in[23];
  const float* cm_b1 = (const float*)d_in[24];
  const float* cm_W2 = (const float*)d_in[25];
  const float* cm_b2 = (const float*)d_in[26];
  const float* cm_W3 = (const float*)d_in[27];
  const float* cm_b3 = (const float*)d_in[28];
  float* out = (float*)d_out;

  float* hoI = (float*)d_ws;                 // 512*40*64 floats
  float* hiI = hoI + (size_t)512 * 40 * 64;  // 512*64 floats
  int* cnt = (int*)(hiI + (size_t)512 * 64); // 512 ints

  hipMemsetAsync(cnt, 0, 512 * sizeof(int), stream);

  // Fused: S (1024 blocks x 20 q-groups) + I (128 blocks x 4 groups) + tails.
  agg_kernel<<<1024 + 128, 256, 0, stream>>>(
      1024, u_user_item_pad, u_user_pad, u_item_pad, uids,
      user_table, item_table, rate_table,
      gv_W1, gv_b1, gv_W2, gv_b2,
      atti_W1, atti_b1, atti_W2, atti_b2,
      agg_W, agg_b,
      attu_W1, attu_b1, attu_W2, attu_b2,
      aggn_W, aggn_b,
      cm_W1, cm_b1, cm_W2, cm_b2, cm_W3, cm_b3,
      u_user_pad, hoI, hiI, cnt, out);
}

// Round 8
// 290.807 us; speedup vs baseline: 1.5134x; 1.5134x over previous
//
#include <hip/hip_runtime.h>
#include <math.h>

#define EPSV 1e-10f

typedef _Float16 f16x8 __attribute__((ext_vector_type(8)));
typedef _Float16 f16x4 __attribute__((ext_vector_type(4)));
typedef float f32x4 __attribute__((ext_vector_type(4)));

// ---------------- agg LDS layout (bytes) ----------------
#define OFF_W1T  0       // 16384: W1t[n][k] f16 swz      (P0: AU f32 64x64)
#define OFF_W2T  16384   // 8192:  W2t[n2][h] f16 swz
#define OFF_M2T  24576   // 8192:  M2t[n3][h] f16 swz (M2 = W2 . AW1x)
#define OFF_X    32768   // 16384: 4 wave-slots x 4096B: H tile rows (16 x 256B)
                         //        (P0: uS f32; P2a: cst partials 4x64 f32)
#define OFF_V    49152   // 5120:  sV[g][n], g < 16
#define SMEM_SZ  54272   // 2 blocks/CU (VGPR-limited anyway)

__device__ __forceinline__ f16x8 cvt_f16x8(const float4 a, const float4 b) {
  f16x8 h;
  h[0] = (_Float16)a.x; h[1] = (_Float16)a.y; h[2] = (_Float16)a.z; h[3] = (_Float16)a.w;
  h[4] = (_Float16)b.x; h[5] = (_Float16)b.y; h[6] = (_Float16)b.z; h[7] = (_Float16)b.w;
  return h;
}

// ---------------------------------------------------------------------------
// Fused item-aggregation. S-blocks [0,nSblk): 16 groups (G=48,P=40, 4/wave);
// I-blocks after: 4 groups (G=128,P=100, 1/wave). 256 thr = 4 waves.
// Wave owns whole groups -> zero __syncthreads in the main loop.
// R8: W1 A-frags + M2 B-frags live in REGISTERS (hoisted once); the In tile
// is gathered from global STRAIGHT INTO B-frag registers (per-lane fragment
// = 4x8 consecutive floats of one row) -> no LDS staging for In; masks via
// __shfl. LDS in the main loop = H round-trip + W2 frags only.
// ---------------------------------------------------------------------------
__global__ __launch_bounds__(256, 2) void agg_kernel(
    const int nSblk,
    const int* __restrict__ idsS, const int* __restrict__ uidS,
    const int* __restrict__ idsI, const int* __restrict__ uidI,
    const float* __restrict__ user_table, const float* __restrict__ item_table,
    const float* __restrict__ rate_table,
    const float* __restrict__ gv_W1, const float* __restrict__ gv_b1,
    const float* __restrict__ gv_W2, const float* __restrict__ gv_b2,
    const float* __restrict__ atti_W1, const float* __restrict__ atti_b1,
    const float* __restrict__ atti_W2, const float* __restrict__ atti_b2,
    const float* __restrict__ agg_W, const float* __restrict__ agg_b,
    float* __restrict__ outS, float* __restrict__ outI) {
  __shared__ __align__(16) char smem[SMEM_SZ];
  const int tid = threadIdx.x;
  const int wave = tid >> 6, lane = tid & 63;
  const int quad = lane >> 4, mrow = lane & 15;

  const bool isS = (int)blockIdx.x < nSblk;
  const int NG = isS ? 16 : 4;
  const int P = isS ? 40 : 100;
  const int nGrp = isS ? 4 : 1;  // groups per wave
  const int tpg = isS ? 3 : 8;   // 16-row tiles per group
  const int* __restrict__ ids = isS ? idsS : idsI;
  const int* __restrict__ uidp = isS ? uidS : uidI;
  float* __restrict__ out = isS ? outS : outI;
  const int gbase = isS ? (int)blockIdx.x * 16 : ((int)blockIdx.x - nSblk) * 4;

  float* sV = (float*)(smem + OFF_V);
  char* smX = smem + OFF_X;
  char* smXw = smX + wave * 4096;  // wave-private H slot
  float* csW = (float*)smXw;       // epilogue c vector (H dead then)

  // ---- P0: uS (X region) + AU = AW1u^T f32 (W1T region, f4-swizzled) ----
  {
    float* uS = (float*)smX;
    float* AU = (float*)(smem + OFF_W1T);
    for (int t = tid; t < NG * 64; t += 256) {
      const int g = t >> 6, f = t & 63;
      uS[t] = user_table[(size_t)uidp[gbase + g] * 64 + f];
    }
    for (int o = tid; o < 1024; o += 256) {  // AU[j][k] = atti_W1[64+k][j]
      const int k = o >> 4, fb = o & 15;
      const float4 v = ((const float4*)(atti_W1 + (64 + k) * 64))[fb];
      const float* vp = (const float*)&v;
#pragma unroll
      for (int c = 0; c < 4; ++c) {
        const int j = fb * 4 + c;
        AU[j * 64 + (((k >> 2) ^ (j & 15)) << 2) + (k & 3)] = vp[c];
      }
    }
  }
  __syncthreads();
  // ---- P1: v[g][j] = u[g] . AW1u[:,j] ----
  {
    const float4* u4 = (const float4*)smX;
    const float4* a4 = (const float4*)(smem + OFF_W1T);
    for (int t = tid; t < NG * 64; t += 256) {
      const int g = t >> 6, j = t & 63;
      float s = 0.f;
#pragma unroll 4
      for (int kb = 0; kb < 16; ++kb) {
        const float4 uu = u4[g * 16 + kb];
        const float4 aa = a4[j * 16 + (kb ^ (j & 15))];
        s += uu.x * aa.x + uu.y * aa.y + uu.z * aa.z + uu.w * aa.w;
      }
      sV[t] = s;
    }
  }
  __syncthreads();
  // ---- P2a: W1T/W2T f16 staging (coalesced) + cst partials -> X ----
  {
    for (int o = tid; o < 2048; o += 256) {  // W1T[n][k], k in 0..127
      const int k = o >> 4, fb = o & 15;
      const float4 v = ((const float4*)(gv_W1 + k * 64))[fb];
      const float* vp = (const float*)&v;
#pragma unroll
      for (int c = 0; c < 4; ++c) {
        const int n = fb * 4 + c;
        *(_Float16*)(smem + OFF_W1T + n * 256 + ((((k >> 3) ^ (n & 7))) << 4) +
                     ((k & 7) << 1)) = (_Float16)vp[c];
      }
    }
    for (int o = tid; o < 1024; o += 256) {  // W2T[n2][h]
      const int h = o >> 4, fb = o & 15;
      const float4 v = ((const float4*)(gv_W2 + h * 64))[fb];
      const float* vp = (const float*)&v;
#pragma unroll
      for (int c = 0; c < 4; ++c) {
        const int n = fb * 4 + c;
        *(_Float16*)(smem + OFF_W2T + n * 128 + ((((h >> 3) ^ (n & 7))) << 4) +
                     ((h & 7) << 1)) = (_Float16)vp[c];
      }
    }
    float* sCstP = (float*)smX;  // uS dead after P1
    const int n = tid & 63, jh = tid >> 6;
    float p = 0.f;
#pragma unroll 4
    for (int jj = 0; jj < 16; ++jj) {
      const int j = jh * 16 + jj;
      p = fmaf(gv_b2[j], atti_W1[j * 64 + n], p);
    }
    sCstP[jh * 64 + n] = p;
  }
  // per-lane constant preloads (global, L2-hot)
  float b1r[16], b2v[4], aw2v[4];
#pragma unroll
  for (int nt = 0; nt < 4; ++nt) {
#pragma unroll
    for (int rg = 0; rg < 4; ++rg) b1r[nt * 4 + rg] = gv_b1[nt * 16 + quad * 4 + rg];
    b2v[nt] = gv_b2[nt * 16 + mrow];
    aw2v[nt] = atti_W2[nt * 16 + mrow];
  }
  const float ab2 = atti_b2[0];

  // ---- gather prefetch: per-lane fragment = row (tile+mrow), 4x8 floats ----
  float4 pf[8];
  float pm;
  auto do_prefetch = [&](int gi2, int tt2) {
    const int g2 = gbase + wave + 4 * gi2;
    const int it = tt2 * 16 + mrow;
    int iid = 0, rid = 0;
    float m = 0.f;
    if (it < P) {
      const int2 pr = ((const int2*)ids)[(size_t)g2 * P + it];
      iid = pr.x; rid = pr.y;
      m = pr.x > 0 ? 1.f : 0.f;
    }
    pm = m;
    const float* ib = item_table + (size_t)iid * 64 + quad * 8;
    const float* rb = rate_table + (size_t)rid * 64 + quad * 8;
    pf[0] = ((const float4*)ib)[0];        pf[1] = ((const float4*)ib)[1];
    pf[2] = ((const float4*)(ib + 32))[0]; pf[3] = ((const float4*)(ib + 32))[1];
    pf[4] = ((const float4*)rb)[0];        pf[5] = ((const float4*)rb)[1];
    pf[6] = ((const float4*)(rb + 32))[0]; pf[7] = ((const float4*)(rb + 32))[1];
  };
  do_prefetch(0, 0);  // in flight across P2b
  __syncthreads();    // B3: W1T/W2T/cstP ready
  // ---- P2b: M2T via MFMA (A,B from L2-hot global) + cstv to registers ----
  float cstv[4];
  {
    f16x8 aM[2];
#pragma unroll
    for (int ks = 0; ks < 2; ++ks) {
      f16x8 t;
#pragma unroll
      for (int j = 0; j < 8; ++j)
        t[j] = (_Float16)atti_W1[(ks * 32 + quad * 8 + j) * 64 + (wave * 16 + mrow)];
      aM[ks] = t;
    }
#pragma unroll
    for (int ht = 0; ht < 4; ++ht) {
      f32x4 c = {0.f, 0.f, 0.f, 0.f};
#pragma unroll
      for (int ks = 0; ks < 2; ++ks) {
        const float* s = gv_W2 + (ht * 16 + mrow) * 64 + ks * 32 + quad * 8;
        f16x8 b;
#pragma unroll
        for (int j = 0; j < 8; ++j) b[j] = (_Float16)s[j];
        c = __builtin_amdgcn_mfma_f32_16x16x32_f16(aM[ks], b, c, 0, 0, 0);
      }
      const int h = ht * 16 + mrow;
#pragma unroll
      for (int rg = 0; rg < 4; ++rg) {
        const int n3 = wave * 16 + quad * 4 + rg;
        *(_Float16*)(smem + OFF_M2T + n3 * 128 + ((((h >> 3) ^ (n3 & 7))) << 4) +
                     ((h & 7) << 1)) = (_Float16)c[rg];
      }
    }
    const float* sCstP = (const float*)smX;
#pragma unroll
    for (int nt = 0; nt < 4; ++nt) {
      const int n = nt * 16 + mrow;
      cstv[nt] = atti_b1[n] + sCstP[n] + sCstP[64 + n] + sCstP[128 + n] +
                 sCstP[192 + n];
    }
  }
  __syncthreads();  // B4: M2T ready; X region free for H tiles

  // ---- hoist W1 A-frags + M2 B-frags into registers (one-time) ----
  f16x8 aW[4][4], bMr[4][2];
#pragma unroll
  for (int nt = 0; nt < 4; ++nt) {
#pragma unroll
    for (int ks = 0; ks < 4; ++ks)
      aW[nt][ks] = *(const f16x8*)(smem + OFF_W1T + (nt * 16 + mrow) * 256 +
                                   (((ks * 4 + quad) ^ (mrow & 7)) << 4));
#pragma unroll
    for (int ks = 0; ks < 2; ++ks)
      bMr[nt][ks] = *(const f16x8*)(smem + OFF_M2T + (nt * 16 + mrow) * 128 +
                                    (((ks * 4 + quad) ^ (mrow & 7)) << 4));
  }

  // =================== barrier-free main loop ===================
  for (int gi = 0; gi < nGrp; ++gi) {
    const int g = wave + 4 * gi;
    float vv[4];
#pragma unroll
    for (int nt = 0; nt < 4; ++nt) vv[nt] = sV[g * 64 + nt * 16 + mrow];
    float pnum[4] = {0.f, 0.f, 0.f, 0.f};
    float pden = 0.f;
    for (int tt = 0; tt < tpg; ++tt) {
      // In B-frags straight from prefetched registers (no LDS)
      f16x8 bIn[4];
      bIn[0] = cvt_f16x8(pf[0], pf[1]);
      bIn[1] = cvt_f16x8(pf[2], pf[3]);
      bIn[2] = cvt_f16x8(pf[4], pf[5]);
      bIn[3] = cvt_f16x8(pf[6], pf[7]);
      const float mcur = pm;
      // issue next prefetch
      {
        int ngi = gi, ntt = tt + 1;
        if (ntt == tpg) { ntt = 0; ngi = gi + 1; }
        if (ngi < nGrp) do_prefetch(ngi, ntt);
      }
      // ---- layer1 (transposed): H^T -> b64 writes to wave-private slot ----
#pragma unroll
      for (int nt = 0; nt < 4; ++nt) {
        f32x4 c = {0.f, 0.f, 0.f, 0.f};
#pragma unroll
        for (int ks = 0; ks < 4; ++ks)
          c = __builtin_amdgcn_mfma_f32_16x16x32_f16(aW[nt][ks], bIn[ks], c, 0, 0, 0);
        f16x4 hv;
#pragma unroll
        for (int rg = 0; rg < 4; ++rg)
          hv[rg] = (_Float16)fmaxf(c[rg] + b1r[nt * 4 + rg], 0.f);
        *(f16x4*)(smXw + mrow * 256 +
                  (((nt * 2 + (quad >> 1)) ^ (mrow & 7)) << 4) +
                  ((quad & 1) << 3)) = hv;
      }
      // ---- H A-frags for layer2 + attention ----
      f16x8 a2[2];
#pragma unroll
      for (int ks = 0; ks < 2; ++ks)
        a2[ks] = *(const f16x8*)(smXw + mrow * 256 +
                                 (((ks * 4 + quad) ^ (mrow & 7)) << 4));
      float mk[4];
#pragma unroll
      for (int rg = 0; rg < 4; ++rg) mk[rg] = __shfl(mcur, quad * 4 + rg);
      f32x4 x2a[4];
      float tl[4] = {0.f, 0.f, 0.f, 0.f};
#pragma unroll
      for (int nt = 0; nt < 4; ++nt) {
        f32x4 c = {0.f, 0.f, 0.f, 0.f}, d = {0.f, 0.f, 0.f, 0.f};
#pragma unroll
        for (int ks = 0; ks < 2; ++ks) {
          const f16x8 bW = *(const f16x8*)(smem + OFF_W2T + (nt * 16 + mrow) * 128 +
                                           (((ks * 4 + quad) ^ (mrow & 7)) << 4));
          c = __builtin_amdgcn_mfma_f32_16x16x32_f16(a2[ks], bW, c, 0, 0, 0);
        }
#pragma unroll
        for (int ks = 0; ks < 2; ++ks)
          d = __builtin_amdgcn_mfma_f32_16x16x32_f16(a2[ks], bMr[nt][ks], d, 0, 0, 0);
#pragma unroll
        for (int rg = 0; rg < 4; ++rg) x2a[nt][rg] = c[rg] + b2v[nt];
#pragma unroll
        for (int rg = 0; rg < 4; ++rg) {
          const float hh = fmaxf(d[rg] + cstv[nt] + mk[rg] * vv[nt], 0.f);
          tl[rg] = fmaf(hh, aw2v[nt], tl[rg]);
        }
      }
      float e[4];
#pragma unroll
      for (int rg = 0; rg < 4; ++rg) {
        float t = tl[rg];
        t += __shfl_xor(t, 1); t += __shfl_xor(t, 2);
        t += __shfl_xor(t, 4); t += __shfl_xor(t, 8);
        e[rg] = __expf(t + ab2) * mk[rg];
        pden += e[rg];
      }
#pragma unroll
      for (int nt = 0; nt < 4; ++nt) {
        pnum[nt] = fmaf(e[0], x2a[nt][0], pnum[nt]);
        pnum[nt] = fmaf(e[1], x2a[nt][1], pnum[nt]);
        pnum[nt] = fmaf(e[2], x2a[nt][2], pnum[nt]);
        pnum[nt] = fmaf(e[3], x2a[nt][3], pnum[nt]);
      }
    }
    // ---- group flush (wave-local): quad-reduce + agg matvec + store ----
    float dsum = pden;
    dsum += __shfl_xor(dsum, 16); dsum += __shfl_xor(dsum, 32);
    const float rd = 1.f / (dsum + EPSV);
#pragma unroll
    for (int nt = 0; nt < 4; ++nt) {
      float s = pnum[nt];
      s += __shfl_xor(s, 16); s += __shfl_xor(s, 32);
      if (quad == 0) csW[nt * 16 + mrow] = s * rd;
    }
    float acc = agg_b[lane];
#pragma unroll 8
    for (int k = 0; k < 64; ++k) acc = fmaf(csW[k], agg_W[k * 64 + lane], acc);
    out[(size_t)(gbase + g) * 64 + lane] = fmaxf(acc, 0.f);
  }
}

// ---------------- stage2 LDS layout (bytes) ----------------
#define S2_W1T 0       // 17408: attu_W1^T f16 [n][k], pitch 272 (bank-rotated)
#define S2_X   17408   // 8704:  2 waves x 16 rows x 272B
#define S2_E   26112   // 128:   2 x 16 f32
#define S2_MSK 26240   // 128:   2 x 16 f32
#define S2_HB  26368   // 1536:  2 x 192 f32 (concat/hidden ping-pong)
#define S2_SZ  27904

// ---------------------------------------------------------------------------
// Kernel 2: beta attention (MFMA) + h_iS + final 3-layer MLP.
// 256 blocks x 128 thr; wave w handles b = blockIdx*2 + w autonomously.
// ---------------------------------------------------------------------------
__global__ __launch_bounds__(128, 2) void stage2_kernel(
    const int* __restrict__ u_user_pad, const float* __restrict__ user_table,
    const float* __restrict__ hoI, const float* __restrict__ hiI,
    const float* __restrict__ attu_W1, const float* __restrict__ attu_b1,
    const float* __restrict__ attu_W2, const float* __restrict__ attu_b2,
    const float* __restrict__ aggn_W, const float* __restrict__ aggn_b,
    const float* __restrict__ cm_W1, const float* __restrict__ cm_b1,
    const float* __restrict__ cm_W2, const float* __restrict__ cm_b2,
    const float* __restrict__ cm_W3, const float* __restrict__ cm_b3,
    float* __restrict__ out) {
  __shared__ __align__(16) char smem[S2_SZ];
  const int tid = threadIdx.x;
  const int wave = tid >> 6, lane = tid & 63;
  const int quad = lane >> 4, mrow = lane & 15;
  const int b = (int)blockIdx.x * 2 + wave;

  char* sW1 = smem + S2_W1T;
  char* sXw = smem + S2_X + wave * 4352;
  float* sE = (float*)(smem + S2_E) + wave * 16;
  float* sM = (float*)(smem + S2_MSK) + wave * 16;
  float* sB = (float*)(smem + S2_HB) + wave * 192;

  for (int o = tid; o < 2048; o += 128) {
    const int k = o >> 4, fb = o & 15;
    const float4 v = ((const float4*)(attu_W1 + k * 64))[fb];
    const float* vp = (const float*)&v;
#pragma unroll
    for (int c = 0; c < 4; ++c) {
      const int n = fb * 4 + c;
      *(_Float16*)(sW1 + n * 272 + ((k >> 3) << 4) + ((k & 7) << 1)) = (_Float16)vp[c];
    }
  }
  float b1v[4], w2v[4];
#pragma unroll
  for (int nt = 0; nt < 4; ++nt) {
    b1v[nt] = attu_b1[nt * 16 + mrow];
    w2v[nt] = attu_W2[nt * 16 + mrow];
  }
  const float b2s = attu_b2[0];

  float4 pa[4], pb[4];
  float msk[4];
  auto pf = [&](int tt) {
#pragma unroll
    for (int k = 0; k < 4; ++k) {
      const int u = lane + (k << 6);
      const int r = u >> 4, bb = u & 15;
      const int q = tt * 16 + r;
      const int qc = q < 40 ? q : 39;
      int uid = 0;
      float m = 0.f;
      if (q < 40) {
        uid = u_user_pad[b * 40 + q];
        m = uid > 0 ? 1.f : 0.f;
      }
      msk[k] = m;
      const float* src = (bb < 8)
                             ? hoI + ((size_t)b * 40 + qc) * 64 + bb * 8
                             : user_table + (size_t)uid * 64 + (bb - 8) * 8;
      pa[k] = ((const float4*)src)[0];
      pb[k] = ((const float4*)src)[1];
    }
  };
  pf(0);
  __syncthreads();  // W1T ready

  float numer = 0.f, pden = 0.f;
  for (int tt = 0; tt < 3; ++tt) {
#pragma unroll
    for (int k = 0; k < 4; ++k) {
      const int u = lane + (k << 6);
      const int r = u >> 4, bb = u & 15;
      *(f16x8*)(sXw + r * 272 + (bb << 4)) = cvt_f16x8(pa[k], pb[k]);
      if (bb == 0) sM[r] = msk[k];
    }
    if (tt < 2) pf(tt + 1);
    f16x8 a[4];
#pragma unroll
    for (int ks = 0; ks < 4; ++ks)
      a[ks] = *(const f16x8*)(sXw + mrow * 272 + ((ks * 4 + quad) << 4));
    float mk[4];
#pragma unroll
    for (int rg = 0; rg < 4; ++rg) mk[rg] = sM[quad * 4 + rg];
    float tl[4] = {0.f, 0.f, 0.f, 0.f};
#pragma unroll
    for (int nt = 0; nt < 4; ++nt) {
      f32x4 d = {0.f, 0.f, 0.f, 0.f};
      const int n = nt * 16 + mrow;
#pragma unroll
      for (int ks = 0; ks < 4; ++ks) {
        const f16x8 bW = *(const f16x8*)(sW1 + n * 272 + ((ks * 4 + quad) << 4));
        d = __builtin_amdgcn_mfma_f32_16x16x32_f16(a[ks], bW, d, 0, 0, 0);
      }
#pragma unroll
      for (int rg = 0; rg < 4; ++rg) {
        const float h = fmaxf(d[rg] + b1v[nt], 0.f);
        tl[rg] = fmaf(h, w2v[nt], tl[rg]);
      }
    }
    float e[4];
#pragma unroll
    for (int rg = 0; rg < 4; ++rg) {
      float t = tl[rg];
      t += __shfl_xor(t, 1); t += __shfl_xor(t, 2);
      t += __shfl_xor(t, 4); t += __shfl_xor(t, 8);
      e[rg] = __expf(t + b2s) * mk[rg];
      pden += e[rg];
    }
    if (mrow == 0) {
#pragma unroll
      for (int rg = 0; rg < 4; ++rg) sE[quad * 4 + rg] = e[rg];
    }
#pragma unroll 4
    for (int r = 0; r < 16; ++r) {
      const float er = sE[r];
      const float xv = (float)*(const _Float16*)(sXw + r * 272 + ((lane >> 3) << 4) +
                                                 ((lane & 7) << 1));
      numer = fmaf(er, xv, numer);
    }
  }
  pden += __shfl_xor(pden, 16);
  pden += __shfl_xor(pden, 32);
  const float hagg = numer / (pden + EPSV);

  sB[128 + lane] = hagg;
  sB[lane] = hiI[(size_t)b * 64 + lane];
  float acc = aggn_b[lane];
#pragma unroll 8
  for (int k = 0; k < 64; ++k) acc = fmaf(sB[128 + k], aggn_W[k * 64 + lane], acc);
  sB[64 + lane] = fmaxf(acc, 0.f);
  float c1 = cm_b1[lane];
#pragma unroll 8
  for (int k = 0; k < 128; ++k) c1 = fmaf(sB[k], cm_W1[k * 64 + lane], c1);
  sB[128 + lane] = fmaxf(c1, 0.f);
  float c2 = cm_b2[lane];
#pragma unroll 8
  for (int k = 0; k < 64; ++k) c2 = fmaf(sB[128 + k], cm_W2[k * 64 + lane], c2);
  sB[lane] = fmaxf(c2, 0.f);
  float c3 = cm_b3[lane];
#pragma unroll 8
  for (int k = 0; k < 64; ++k) c3 = fmaf(sB[k], cm_W3[k * 64 + lane], c3);
  out[(size_t)b * 64 + lane] = fmaxf(c3, 0.f);
}

extern "C" void kernel_launch(void* const* d_in, const int* in_sizes, int n_in,
                              void* d_out, int out_size, void* d_ws, size_t ws_size,
                              hipStream_t stream) {
  const int* uids = (const int*)d_in[0];
  const int* u_item_pad = (const int*)d_in[1];
  const int* u_user_pad = (const int*)d_in[2];
  const int* u_user_item_pad = (const int*)d_in[3];
  const float* user_table = (const float*)d_in[4];
  const float* item_table = (const float*)d_in[5];
  const float* rate_table = (const float*)d_in[6];
  const float* gv_W1 = (const float*)d_in[7];
  const float* gv_b1 = (const float*)d_in[8];
  const float* gv_W2 = (const float*)d_in[9];
  const float* gv_b2 = (const float*)d_in[10];
  const float* atti_W1 = (const float*)d_in[11];
  const float* atti_b1 = (const float*)d_in[12];
  const float* atti_W2 = (const float*)d_in[13];
  const float* atti_b2 = (const float*)d_in[14];
  const float* agg_W = (const float*)d_in[15];
  const float* agg_b = (const float*)d_in[16];
  const float* attu_W1 = (const float*)d_in[17];
  const float* attu_b1 = (const float*)d_in[18];
  const float* attu_W2 = (const float*)d_in[19];
  const float* attu_b2 = (const float*)d_in[20];
  const float* aggn_W = (const float*)d_in[21];
  const float* aggn_b = (const float*)d_in[22];
  const float* cm_W1 = (const float*)d_in[23];
  const float* cm_b1 = (const float*)d_in[24];
  const float* cm_W2 = (const float*)d_in[25];
  const float* cm_b2 = (const float*)d_in[26];
  const float* cm_W3 = (const float*)d_in[27];
  const float* cm_b3 = (const float*)d_in[28];
  float* out = (float*)d_out;

  float* hoI = (float*)d_ws;                 // 512*40*64 floats
  float* hiI = hoI + (size_t)512 * 40 * 64;  // 512*64 floats

  // Merged S (1280 blocks x 16 groups) + I (128 blocks x 4 groups).
  agg_kernel<<<1280 + 128, 256, 0, stream>>>(
      1280, u_user_item_pad, u_user_pad, u_item_pad, uids,
      user_table, item_table, rate_table,
      gv_W1, gv_b1, gv_W2, gv_b2,
      atti_W1, atti_b1, atti_W2, atti_b2,
      agg_W, agg_b, hoI, hiI);
  // Beta attention + h_iS + final MLP (wave-autonomous MFMA).
  stage2_kernel<<<256, 128, 0, stream>>>(u_user_pad, user_table, hoI, hiI,
                                         attu_W1, attu_b1, attu_W2, attu_b2,
                                         aggn_W, aggn_b,
                                         cm_W1, cm_b1, cm_W2, cm_b2, cm_W3, cm_b3,
                                         out);
}